// Round 1
// baseline (304.111 us; speedup 1.0000x reference)
//
#include <hip/hip_runtime.h>
#include <hip/hip_bf16.h>

#define NMOL    2048
#define MOLSIZE 100
#define MOL2    (MOLSIZE * MOLSIZE)   // 10000
#define CUTOFF2 9.0f                  // OUTERCUTOFF^2

// ws layout (int32):
// [0          .. NMOL)   : per-molecule real-atom count
// [NMOL       .. 2*NMOL) : per-molecule selected-pair count
// [2*NMOL     .. 3*NMOL) : exclusive atom base
// [3*NMOL     .. 4*NMOL) : exclusive pair base
// [4*NMOL]               : n_real total
// [4*NMOL+1]             : npairs total

__global__ __launch_bounds__(256) void k_count(const int* __restrict__ species,
                                               const float* __restrict__ coords,
                                               float* __restrict__ out,
                                               int* __restrict__ ws) {
    const int m = blockIdx.x;
    const int tid = threadIdx.x;
    const int lane = tid & 63, wv = tid >> 6;

    __shared__ float sc[MOLSIZE * 3];
    __shared__ int   ssp[MOLSIZE];
    __shared__ int   s_nb[4], s_hv[4], s_hy[4], s_pc[4];

    for (int t = tid; t < MOLSIZE * 3; t += 256)
        sc[t] = coords[(size_t)m * (MOLSIZE * 3) + t];
    for (int t = tid; t < MOLSIZE; t += 256)
        ssp[t] = species[m * MOLSIZE + t];
    __syncthreads();

    // atom-level counts (threads 0..99 carry flags; others contribute 0)
    const int sp = (tid < MOLSIZE) ? ssp[tid] : 0;
    unsigned long long bnb = __ballot(sp > 0);
    unsigned long long bhv = __ballot(sp > 1);
    unsigned long long bhy = __ballot(sp == 1);
    if (lane == 0) { s_nb[wv] = __popcll(bnb); s_hv[wv] = __popcll(bhv); s_hy[wv] = __popcll(bhy); }

    // pair counting (order irrelevant here)
    int cnt = 0;
    for (int p = tid; p < MOL2; p += 256) {
        const int i = p / MOLSIZE;
        const int j = p - i * MOLSIZE;
        if (i >= j) continue;
        if (ssp[i] <= 0 || ssp[j] <= 0) continue;
        const float dx = __fsub_rn(sc[j * 3 + 0], sc[i * 3 + 0]);
        const float dy = __fsub_rn(sc[j * 3 + 1], sc[i * 3 + 1]);
        const float dz = __fsub_rn(sc[j * 3 + 2], sc[i * 3 + 2]);
        const float d2 = __fadd_rn(__fadd_rn(__fmul_rn(dx, dx), __fmul_rn(dy, dy)),
                                   __fmul_rn(dz, dz));
        if (d2 < CUTOFF2) ++cnt;
    }
    for (int o = 32; o > 0; o >>= 1) cnt += __shfl_down(cnt, o);
    if (lane == 0) s_pc[wv] = cnt;
    __syncthreads();

    if (tid == 0) {
        ws[m]        = s_nb[0] + s_nb[1] + s_nb[2] + s_nb[3];
        ws[NMOL + m] = s_pc[0] + s_pc[1] + s_pc[2] + s_pc[3];
        out[2 + m]          = (float)(s_hv[0] + s_hv[1] + s_hv[2] + s_hv[3]);  // nHeavy
        out[2 + NMOL + m]   = (float)(s_hy[0] + s_hy[1] + s_hy[2] + s_hy[3]);  // nHydro
        if (m == 0) { out[0] = (float)NMOL; out[1] = (float)MOLSIZE; }
    }
}

__global__ __launch_bounds__(256) void k_scan(int* __restrict__ ws) {
    const int tid = threadIdx.x, lane = tid & 63, wv = tid >> 6;
    __shared__ int wsum[4];
    for (int which = 0; which < 2; ++which) {
        const int* src = ws + which * NMOL;
        int*       dst = ws + (2 + which) * NMOL;
        int run = 0;
        for (int base = 0; base < NMOL; base += 256) {
            const int v = src[base + tid];
            int x = v;
            for (int o = 1; o < 64; o <<= 1) { int y = __shfl_up(x, o); if (lane >= o) x += y; }
            if (lane == 63) wsum[wv] = x;
            __syncthreads();
            int add = 0;
            for (int w = 0; w < wv; ++w) add += wsum[w];
            const int tot = wsum[0] + wsum[1] + wsum[2] + wsum[3];
            dst[base + tid] = run + add + (x - v);   // exclusive
            run += tot;
            __syncthreads();
        }
        if (tid == 0) ws[4 * NMOL + which] = run;
    }
}

__global__ __launch_bounds__(256) void k_write(const int* __restrict__ species,
                                               const float* __restrict__ coords,
                                               const float* __restrict__ lcf_p,
                                               float* __restrict__ out,
                                               const int* __restrict__ ws) {
    const int m = blockIdx.x;
    const int tid = threadIdx.x;
    const int lane = tid & 63, wv = tid >> 6;

    __shared__ float sc[MOLSIZE * 3];
    __shared__ int   ssp[MOLSIZE];
    __shared__ int   srank[MOLSIZE];
    __shared__ int   wcnt[4];

    for (int t = tid; t < MOLSIZE * 3; t += 256)
        sc[t] = coords[(size_t)m * (MOLSIZE * 3) + t];
    for (int t = tid; t < MOLSIZE; t += 256)
        ssp[t] = species[m * MOLSIZE + t];
    __syncthreads();

    const int atomBase = ws[2 * NMOL + m];
    const int pairBase = ws[3 * NMOL + m];
    const int nReal    = ws[4 * NMOL];
    const int nPairs   = ws[4 * NMOL + 1];
    const float lcf    = lcf_p[0];

    // output offsets (all float32, concatenated in return order)
    const size_t off_Z      = 2 + 2 * (size_t)NMOL;          // 4098
    const size_t off_maskd  = off_Z + (size_t)nReal;
    const size_t off_amolid = off_Z + 2 * (size_t)nReal;
    const size_t off_mask   = off_Z + 3 * (size_t)nReal;
    const size_t off_pmolid = off_mask + 1 * (size_t)nPairs;
    const size_t off_ni     = off_mask + 2 * (size_t)nPairs;
    const size_t off_nj     = off_mask + 3 * (size_t)nPairs;
    const size_t off_idxi   = off_mask + 4 * (size_t)nPairs;
    const size_t off_idxj   = off_mask + 5 * (size_t)nPairs;
    const size_t off_xij    = off_mask + 6 * (size_t)nPairs;
    const size_t off_rij    = off_mask + 9 * (size_t)nPairs;

    // ---- atom compaction (ascending flat index) ----
    const int aflag = (tid < MOLSIZE) && (ssp[tid] > 0);
    {
        unsigned long long b = __ballot(aflag);
        const int lanePre = __popcll(b & ((1ull << lane) - 1ull));
        if (lane == 0) wcnt[wv] = __popcll(b);
        __syncthreads();
        int wbase = 0;
        for (int w = 0; w < wv; ++w) wbase += wcnt[w];
        if (aflag) {
            const int r = wbase + lanePre;
            srank[tid] = r;
            const int a = m * MOLSIZE + tid;                 // flat atom index
            const size_t g = (size_t)atomBase + r;
            out[off_Z + g]      = (float)ssp[tid];
            out[off_maskd + g]  = (float)(a * MOLSIZE + tid);
            out[off_amolid + g] = (float)m;
        }
        __syncthreads();  // srank visible; wcnt free for reuse
    }

    // ---- ordered pair compaction ----
    int run = pairBase;
    for (int base = 0; base < MOL2; base += 256) {
        const int p = base + tid;
        const int i = p / MOLSIZE;
        const int j = p - i * MOLSIZE;
        float dx = 0.f, dy = 0.f, dz = 0.f, d2 = 0.f;
        bool flag = false;
        if (p < MOL2 && i < j && ssp[i] > 0 && ssp[j] > 0) {
            dx = __fsub_rn(sc[j * 3 + 0], sc[i * 3 + 0]);
            dy = __fsub_rn(sc[j * 3 + 1], sc[i * 3 + 1]);
            dz = __fsub_rn(sc[j * 3 + 2], sc[i * 3 + 2]);
            d2 = __fadd_rn(__fadd_rn(__fmul_rn(dx, dx), __fmul_rn(dy, dy)),
                           __fmul_rn(dz, dz));
            flag = d2 < CUTOFF2;
        }
        unsigned long long bb = __ballot(flag);
        const int lp = __popcll(bb & ((1ull << lane) - 1ull));
        __syncthreads();                 // previous iteration done reading wcnt
        if (lane == 0) wcnt[wv] = __popcll(bb);
        __syncthreads();
        int wb = 0;
        for (int w = 0; w < wv; ++w) wb += wcnt[w];
        const int tot = wcnt[0] + wcnt[1] + wcnt[2] + wcnt[3];
        if (flag) {
            const int r = run + wb + lp;
            const float pd = __fmul_rn(d2, d2);              // square, not sqrt (faithful)
            out[off_mask + r]   = (float)((m * MOLSIZE + i) * MOLSIZE + j);
            out[off_pmolid + r] = (float)m;
            out[off_ni + r]     = (float)ssp[i];
            out[off_nj + r]     = (float)ssp[j];
            out[off_idxi + r]   = (float)(atomBase + srank[i]);
            out[off_idxj + r]   = (float)(atomBase + srank[j]);
            out[off_xij + 3 * (size_t)r + 0] = __fdiv_rn(dx, pd);
            out[off_xij + 3 * (size_t)r + 1] = __fdiv_rn(dy, pd);
            out[off_xij + 3 * (size_t)r + 2] = __fdiv_rn(dz, pd);
            out[off_rij + r]    = __fmul_rn(pd, lcf);
        }
        run += tot;
    }
}

extern "C" void kernel_launch(void* const* d_in, const int* in_sizes, int n_in,
                              void* d_out, int out_size, void* d_ws, size_t ws_size,
                              hipStream_t stream) {
    const int*   species = (const int*)d_in[0];
    const float* coords  = (const float*)d_in[1];
    // d_in[2] = tore (unused: only feeds the even-electron assert, always passes)
    const float* lcf     = (const float*)d_in[3];
    float*       out     = (float*)d_out;
    int*         ws      = (int*)d_ws;

    k_count<<<dim3(NMOL), dim3(256), 0, stream>>>(species, coords, out, ws);
    k_scan <<<dim3(1),    dim3(256), 0, stream>>>(ws);
    k_write<<<dim3(NMOL), dim3(256), 0, stream>>>(species, coords, lcf, out, ws);
}